// Round 2
// baseline (261.194 us; speedup 1.0000x reference)
//
#include <hip/hip_runtime.h>

#define POOL_H 7
#define POOL_W 7
#define SR 2            // sampling ratio
#define SCALE 0.25f
#define NC 2            // channels per thread

typedef float f2v __attribute__((ext_vector_type(2)));
// 4-byte-aligned float2 so the compiler may emit an (unaligned-ok) dwordx2
typedef f2v uf2 __attribute__((aligned(4)));

// One thread per (k, c-pair, ph, pw). Each thread computes NC channels that
// share identical sample geometry; corner pairs loaded as one float2.
__global__ __launch_bounds__(256) void roi_align_kernel(
    const float* __restrict__ feat,   // [N][C][H][W]
    const float* __restrict__ rois,   // [K][5]
    float* __restrict__ out,          // [K][C][POOL_H][POOL_W]
    int C, int H, int W, int K)
{
    int idx = blockIdx.x * blockDim.x + threadIdx.x;
    int cgroups = C / NC;
    int per_k = cgroups * POOL_H * POOL_W;
    int total = K * per_k;
    if (idx >= total) return;

    int pw = idx % POOL_W;
    int ph = (idx / POOL_W) % POOL_H;
    int c2 = (idx / (POOL_W * POOL_H)) % cgroups;
    int k  = idx / per_k;

    const float* r = rois + (size_t)k * 5;
    int b = (int)r[0];
    float rx1 = r[1] * SCALE - 0.5f;
    float ry1 = r[2] * SCALE - 0.5f;
    float rx2 = r[3] * SCALE - 0.5f;
    float ry2 = r[4] * SCALE - 0.5f;
    float bin_h = (ry2 - ry1) * (1.0f / POOL_H);
    float bin_w = (rx2 - rx1) * (1.0f / POOL_W);

    // y geometry (SR samples)
    int   yr0[SR], yr1[SR];
    float ly[SR], hy[SR];
    bool  vy[SR];
    #pragma unroll
    for (int iy = 0; iy < SR; ++iy) {
        float y = ry1 + ((float)ph + ((float)iy + 0.5f) * (1.0f / SR)) * bin_h;
        vy[iy] = (y > -1.0f) && (y < (float)H);
        float yc = fminf(fmaxf(y, 0.0f), (float)(H - 1));
        int y0 = (int)yc;                 // yc >= 0, trunc == floor
        yr0[iy] = y0;
        yr1[iy] = min(y0 + 1, H - 1);
        ly[iy] = yc - (float)y0;
        hy[iy] = 1.0f - ly[iy];
    }

    // x geometry (SR samples); merged-load trick:
    //   xl = min(x0, W-2); d = float2 at xl;
    //   v00 = (x0>xl) ? d.y : d.x;  v01 = d.y  (xi1 == xl+1 in both cases)
    int   xl[SR];
    float lx[SR];
    bool  vx[SR], xhi[SR];
    #pragma unroll
    for (int ix = 0; ix < SR; ++ix) {
        float x = rx1 + ((float)pw + ((float)ix + 0.5f) * (1.0f / SR)) * bin_w;
        vx[ix] = (x > -1.0f) && (x < (float)W);
        float xc = fminf(fmaxf(x, 0.0f), (float)(W - 1));
        int x0 = (int)xc;
        int xload = min(x0, W - 2);
        xl[ix] = xload;
        xhi[ix] = (x0 > xload);
        lx[ix] = xc - (float)x0;
    }

    const size_t HW = (size_t)H * W;
    const float* fmap = feat + ((size_t)b * C + (size_t)c2 * NC) * HW;

    float acc[NC];
    #pragma unroll
    for (int cc = 0; cc < NC; ++cc) acc[cc] = 0.0f;

    #pragma unroll
    for (int iy = 0; iy < SR; ++iy) {
        #pragma unroll
        for (int ix = 0; ix < SR; ++ix) {
            if (vy[iy] && vx[ix]) {
                int off0 = yr0[iy] * W + xl[ix];
                int off1 = yr1[iy] * W + xl[ix];
                #pragma unroll
                for (int cc = 0; cc < NC; ++cc) {
                    const float* base = fmap + (size_t)cc * HW;
                    f2v d0 = *(const uf2*)(base + off0);
                    f2v d1 = *(const uf2*)(base + off1);
                    float v00 = xhi[ix] ? d0.y : d0.x;
                    float v10 = xhi[ix] ? d1.y : d1.x;
                    // bilinear along x (lerp form), then along y
                    float r0 = v00 + lx[ix] * (d0.y - v00);
                    float r1 = v10 + lx[ix] * (d1.y - v10);
                    acc[cc] += hy[iy] * r0 + ly[iy] * r1;
                }
            }
        }
    }

    size_t obase = ((size_t)k * C + (size_t)c2 * NC) * (POOL_H * POOL_W)
                 + ph * POOL_W + pw;
    #pragma unroll
    for (int cc = 0; cc < NC; ++cc)
        out[obase + (size_t)cc * (POOL_H * POOL_W)] = acc[cc] * (1.0f / (SR * SR));
}

extern "C" void kernel_launch(void* const* d_in, const int* in_sizes, int n_in,
                              void* d_out, int out_size, void* d_ws, size_t ws_size,
                              hipStream_t stream) {
    const float* feat = (const float*)d_in[0];
    const float* rois = (const float*)d_in[1];
    float* out = (float*)d_out;

    const int C = 256, H = 200, W = 200;
    const int K = in_sizes[1] / 5;

    int total = K * (C / NC) * POOL_H * POOL_W;
    int block = 256;
    int grid = (total + block - 1) / block;
    roi_align_kernel<<<grid, block, 0, stream>>>(feat, rois, out, C, H, W, K);
}

// Round 3
// 120.767 us; speedup vs baseline: 2.1628x; 2.1628x over previous
//
#include <hip/hip_runtime.h>

#define POOL_H 7
#define POOL_W 7
#define BINS   (POOL_H * POOL_W)
#define SR 2            // sampling ratio
#define SCALE 0.25f
#define NC 2            // channels per thread
#define NXCD 8

typedef float f2v __attribute__((ext_vector_type(2)));
typedef f2v uf2 __attribute__((aligned(4)));

// Loop-nest inverted for L2 locality: channel-pair (slice) is OUTERMOST,
// grouped per-XCD so each XCD's private L2 holds one slice's working set
// (2 planes x 4 images ~ 1.28 MB << 4 MB) while all 1024 ROIs sweep it.
__global__ __launch_bounds__(256) void roi_align_kernel(
    const float* __restrict__ feat,   // [N][C][H][W]
    const float* __restrict__ rois,   // [K][5]
    float* __restrict__ out,          // [K][C][POOL_H][POOL_W]
    int C, int H, int W, int K,
    int blocks_per_slice, int slices_per_xcd)
{
    // wgid % 8 = XCD under round-robin dispatch (learn_hip m09/m157).
    // XCD g owns slices [g*spx, (g+1)*spx), processed sequentially.
    int wgid  = blockIdx.x;
    int g     = wgid % NXCD;
    int r     = wgid / NXCD;
    int slice = g * slices_per_xcd + r / blocks_per_slice;   // c-pair index
    int j     = r % blocks_per_slice;

    int tid = j * (int)blockDim.x + (int)threadIdx.x;  // within slice: K*BINS
    int k   = tid / BINS;
    int bin = tid % BINS;
    if (k >= K) return;
    int pw = bin % POOL_W;
    int ph = bin / POOL_W;
    int c2 = slice;

    const float* rp = rois + (size_t)k * 5;
    int b = (int)rp[0];
    float rx1 = rp[1] * SCALE - 0.5f;
    float ry1 = rp[2] * SCALE - 0.5f;
    float rx2 = rp[3] * SCALE - 0.5f;
    float ry2 = rp[4] * SCALE - 0.5f;
    float bin_h = (ry2 - ry1) * (1.0f / POOL_H);
    float bin_w = (rx2 - rx1) * (1.0f / POOL_W);

    // y geometry (SR samples)
    int   yr0[SR], yr1[SR];
    float ly[SR], hy[SR];
    bool  vy[SR];
    #pragma unroll
    for (int iy = 0; iy < SR; ++iy) {
        float y = ry1 + ((float)ph + ((float)iy + 0.5f) * (1.0f / SR)) * bin_h;
        vy[iy] = (y > -1.0f) && (y < (float)H);
        float yc = fminf(fmaxf(y, 0.0f), (float)(H - 1));
        int y0 = (int)yc;
        yr0[iy] = y0;
        yr1[iy] = min(y0 + 1, H - 1);
        ly[iy] = yc - (float)y0;
        hy[iy] = 1.0f - ly[iy];
    }

    // x geometry (SR samples); merged-load trick:
    //   xl = min(x0, W-2); d = float2 at xl;
    //   v00 = (x0>xl) ? d.y : d.x;  v01 = d.y (xi1 == xl+1 in both cases)
    int   xl[SR];
    float lx[SR];
    bool  vx[SR], xhi[SR];
    #pragma unroll
    for (int ix = 0; ix < SR; ++ix) {
        float x = rx1 + ((float)pw + ((float)ix + 0.5f) * (1.0f / SR)) * bin_w;
        vx[ix] = (x > -1.0f) && (x < (float)W);
        float xc = fminf(fmaxf(x, 0.0f), (float)(W - 1));
        int x0 = (int)xc;
        int xload = min(x0, W - 2);
        xl[ix] = xload;
        xhi[ix] = (x0 > xload);
        lx[ix] = xc - (float)x0;
    }

    const size_t HW = (size_t)H * W;
    const float* fmap = feat + ((size_t)b * C + (size_t)c2 * NC) * HW;

    float acc[NC];
    #pragma unroll
    for (int cc = 0; cc < NC; ++cc) acc[cc] = 0.0f;

    #pragma unroll
    for (int iy = 0; iy < SR; ++iy) {
        #pragma unroll
        for (int ix = 0; ix < SR; ++ix) {
            if (vy[iy] && vx[ix]) {
                int off0 = yr0[iy] * W + xl[ix];
                int off1 = yr1[iy] * W + xl[ix];
                #pragma unroll
                for (int cc = 0; cc < NC; ++cc) {
                    const float* base = fmap + (size_t)cc * HW;
                    f2v d0 = *(const uf2*)(base + off0);
                    f2v d1 = *(const uf2*)(base + off1);
                    float v00 = xhi[ix] ? d0.y : d0.x;
                    float v10 = xhi[ix] ? d1.y : d1.x;
                    float r0 = v00 + lx[ix] * (d0.y - v00);
                    float r1 = v10 + lx[ix] * (d1.y - v10);
                    acc[cc] += hy[iy] * r0 + ly[iy] * r1;
                }
            }
        }
    }

    size_t obase = ((size_t)k * C + (size_t)c2 * NC) * BINS + bin;
    #pragma unroll
    for (int cc = 0; cc < NC; ++cc)
        out[obase + (size_t)cc * BINS] = acc[cc] * (1.0f / (SR * SR));
}

extern "C" void kernel_launch(void* const* d_in, const int* in_sizes, int n_in,
                              void* d_out, int out_size, void* d_ws, size_t ws_size,
                              hipStream_t stream) {
    const float* feat = (const float*)d_in[0];
    const float* rois = (const float*)d_in[1];
    float* out = (float*)d_out;

    const int C = 256, H = 200, W = 200;
    const int K = in_sizes[1] / 5;

    const int slices = C / NC;                       // 128
    const int threads_per_slice = K * BINS;          // 50176
    const int block = 256;
    const int blocks_per_slice = (threads_per_slice + block - 1) / block; // 196
    const int slices_per_xcd = slices / NXCD;        // 16
    const int grid = slices * blocks_per_slice;      // 25088

    roi_align_kernel<<<grid, block, 0, stream>>>(feat, rois, out, C, H, W, K,
                                                 blocks_per_slice, slices_per_xcd);
}

// Round 4
// 118.385 us; speedup vs baseline: 2.2063x; 1.0201x over previous
//
#include <hip/hip_runtime.h>

#define POOL_H 7
#define POOL_W 7
#define BINS   49
#define SR 2
#define SCALE 0.25f
#define CH 256          // channels (fixed by problem)

typedef unsigned int   u32;
typedef unsigned short u16;
typedef float f2v __attribute__((ext_vector_type(2)));
typedef f2v uf2 __attribute__((aligned(4)));
typedef float f4  __attribute__((ext_vector_type(4)));
typedef u16  us4 __attribute__((ext_vector_type(4)));
typedef u32  ui2 __attribute__((ext_vector_type(2)));

__device__ __forceinline__ u16 f32_to_bf16_rne(float f) {
    u32 u = __builtin_bit_cast(u32, f);
    u32 r = (u + 0x7FFFu + ((u >> 16) & 1u)) >> 16;
    return (u16)r;
}
__device__ __forceinline__ float bf16lo(u32 u) { return __builtin_bit_cast(float, u << 16); }
__device__ __forceinline__ float bf16hi(u32 u) { return __builtin_bit_cast(float, u & 0xFFFF0000u); }

// ---------------- Pass 1: NCHW f32 -> NHWC bf16 (tiled transpose) -----------
// Tile: 64 hw-positions x 256 channels. Read coalesced along hw, write
// coalesced along c. HW = 40000 divisible by 64 (625 tiles/image).
__global__ __launch_bounds__(256) void nchw_to_nhwc_bf16(
    const float* __restrict__ feat, u16* __restrict__ ft, int HW, int tiles)
{
    int b    = blockIdx.x / tiles;
    int tile = blockIdx.x % tiles;
    int hw0  = tile * 64;

    // pad row to 260 u16 (520 B): 8B-aligned rows, ~4-way write conflict (cheap)
    __shared__ u16 lds[64][260];

    int lane = threadIdx.x & 63;
    int w    = threadIdx.x >> 6;

    const float* src = feat + (size_t)b * CH * HW;
    for (int c = w; c < CH; c += 4) {
        float v = src[(size_t)c * HW + hw0 + lane];
        lds[lane][c] = f32_to_bf16_rne(v);
    }
    __syncthreads();

    u16* dst = ft + ((size_t)b * HW + hw0) * CH;
    // 64 rows x 256 u16 = 32 KB; 16B chunk per thread per iter -> 8 iters
    for (int it = 0; it < 8; ++it) {
        int id = it * 256 + (int)threadIdx.x;   // 16B chunk id, [0,2048)
        int r  = id >> 5;                       // 32 chunks per 512B row
        int o  = (id & 31) * 8;                 // u16 offset within row
        us4 lo = *(const us4*)&lds[r][o];
        us4 hi = *(const us4*)&lds[r][o + 4];
        *(us4*)(dst + (size_t)id * 8)     = lo;
        *(us4*)(dst + (size_t)id * 8 + 4) = hi;
    }
}

// ---------------- Pass 2: gather from NHWC bf16 -----------------------------
// Block = (k, quarter q of the 49 bins). Wave = one bin x all 256 channels:
// lane holds 4 channels; each bilinear corner is ONE uint2 load (8B) within a
// 512B-contiguous wave access -> 8 cache lines/instr (vs ~35 for NCHW).
__global__ __launch_bounds__(256) void roi_gather_nhwc(
    const u16* __restrict__ ft,      // [N][H][W][CH] bf16
    const float* __restrict__ rois,  // [K][5]
    float* __restrict__ out,         // [K][CH][7][7]
    int H, int W, int K)
{
    int k    = blockIdx.x >> 2;
    int q    = blockIdx.x & 3;
    int bin0 = q * 13;
    int nb   = min(BINS - bin0, 13);

    __shared__ float lds[13][CH];    // 13312 B -> 8 blocks/CU

    int lane = threadIdx.x & 63;
    int w    = threadIdx.x >> 6;

    const float* rp = rois + (size_t)k * 5;
    int   b   = (int)rp[0];
    float rx1 = rp[1] * SCALE - 0.5f;
    float ry1 = rp[2] * SCALE - 0.5f;
    float rx2 = rp[3] * SCALE - 0.5f;
    float ry2 = rp[4] * SCALE - 0.5f;
    float bin_h = (ry2 - ry1) * (1.0f / POOL_H);
    float bin_w = (rx2 - rx1) * (1.0f / POOL_W);

    const u16* fbase = ft + (size_t)b * H * W * CH + lane * 4;

    for (int lb = w; lb < nb; lb += 4) {
        int bin = bin0 + lb;
        int ph  = bin / 7;
        int pw  = bin % 7;

        float a0 = 0.f, a1 = 0.f, a2 = 0.f, a3 = 0.f;
        #pragma unroll
        for (int iy = 0; iy < SR; ++iy) {
            float y = ry1 + ((float)ph + ((float)iy + 0.5f) * (1.0f / SR)) * bin_h;
            bool vy = (y > -1.0f) && (y < (float)H);
            float yc = fminf(fmaxf(y, 0.0f), (float)(H - 1));
            int   y0 = (int)yc;
            int   y1 = min(y0 + 1, H - 1);
            float ly = yc - (float)y0;
            float hy = 1.0f - ly;
            #pragma unroll
            for (int ix = 0; ix < SR; ++ix) {
                float x = rx1 + ((float)pw + ((float)ix + 0.5f) * (1.0f / SR)) * bin_w;
                bool vx = (x > -1.0f) && (x < (float)W);
                if (!(vy && vx)) continue;       // wave-uniform branch
                float xc = fminf(fmaxf(x, 0.0f), (float)(W - 1));
                int   x0 = (int)xc;
                int   x1 = min(x0 + 1, W - 1);
                float lx = xc - (float)x0;
                float hx = 1.0f - lx;

                float w00 = hy * hx, w01 = hy * lx, w10 = ly * hx, w11 = ly * lx;
                int p00 = y0 * W + x0, p01 = y0 * W + x1;
                int p10 = y1 * W + x0, p11 = y1 * W + x1;

                #define CORNER(P, WT) {                                   \
                    ui2 u = *(const ui2*)(fbase + (size_t)(P) * CH);      \
                    a0 += (WT) * bf16lo(u.x);  a1 += (WT) * bf16hi(u.x);  \
                    a2 += (WT) * bf16lo(u.y);  a3 += (WT) * bf16hi(u.y);  \
                }
                CORNER(p00, w00); CORNER(p01, w01);
                CORNER(p10, w10); CORNER(p11, w11);
                #undef CORNER
            }
        }
        f4 res = { a0 * 0.25f, a1 * 0.25f, a2 * 0.25f, a3 * 0.25f };
        *(f4*)&lds[lb][lane * 4] = res;          // contiguous 1KB/wave, no conflict
    }
    __syncthreads();

    // Coalesced store: out[k][c][bin0+lb], lb fastest -> contiguous 13-float runs
    float* ob = out + (size_t)k * CH * BINS + bin0;
    for (int id = (int)threadIdx.x; id < 13 * CH; id += 256) {
        int c  = id / 13;
        int lb = id % 13;
        if (lb < nb) ob[(size_t)c * BINS + lb] = lds[lb][c];
    }
}

// ---------------- Fallback (round-3 kernel) if ws too small -----------------
#define NC 2
#define NXCD 8
__global__ __launch_bounds__(256) void roi_align_fallback(
    const float* __restrict__ feat, const float* __restrict__ rois,
    float* __restrict__ out, int C, int H, int W, int K,
    int blocks_per_slice, int slices_per_xcd)
{
    int wgid  = blockIdx.x;
    int g     = wgid % NXCD;
    int r     = wgid / NXCD;
    int slice = g * slices_per_xcd + r / blocks_per_slice;
    int j     = r % blocks_per_slice;
    int tid = j * (int)blockDim.x + (int)threadIdx.x;
    int k   = tid / BINS;
    int bin = tid % BINS;
    if (k >= K) return;
    int pw = bin % POOL_W, ph = bin / POOL_W, c2 = slice;

    const float* rp = rois + (size_t)k * 5;
    int b = (int)rp[0];
    float rx1 = rp[1]*SCALE-0.5f, ry1 = rp[2]*SCALE-0.5f;
    float rx2 = rp[3]*SCALE-0.5f, ry2 = rp[4]*SCALE-0.5f;
    float bin_h = (ry2-ry1)*(1.0f/POOL_H), bin_w = (rx2-rx1)*(1.0f/POOL_W);

    int yr0[SR], yr1[SR]; float ly[SR], hy[SR]; bool vy[SR];
    #pragma unroll
    for (int iy = 0; iy < SR; ++iy) {
        float y = ry1 + ((float)ph + ((float)iy+0.5f)*(1.0f/SR))*bin_h;
        vy[iy] = (y > -1.0f) && (y < (float)H);
        float yc = fminf(fmaxf(y, 0.0f), (float)(H-1));
        int y0 = (int)yc; yr0[iy]=y0; yr1[iy]=min(y0+1,H-1);
        ly[iy]=yc-(float)y0; hy[iy]=1.0f-ly[iy];
    }
    int xl[SR]; float lx[SR]; bool vx[SR], xhi[SR];
    #pragma unroll
    for (int ix = 0; ix < SR; ++ix) {
        float x = rx1 + ((float)pw + ((float)ix+0.5f)*(1.0f/SR))*bin_w;
        vx[ix] = (x > -1.0f) && (x < (float)W);
        float xc = fminf(fmaxf(x, 0.0f), (float)(W-1));
        int x0 = (int)xc; int xload = min(x0, W-2);
        xl[ix]=xload; xhi[ix]=(x0>xload); lx[ix]=xc-(float)x0;
    }
    const size_t HW = (size_t)H*W;
    const float* fmap = feat + ((size_t)b*C + (size_t)c2*NC)*HW;
    float acc[NC]; 
    #pragma unroll
    for (int cc=0; cc<NC; ++cc) acc[cc]=0.0f;
    #pragma unroll
    for (int iy=0; iy<SR; ++iy)
      #pragma unroll
      for (int ix=0; ix<SR; ++ix)
        if (vy[iy] && vx[ix]) {
            int off0 = yr0[iy]*W + xl[ix], off1 = yr1[iy]*W + xl[ix];
            #pragma unroll
            for (int cc=0; cc<NC; ++cc) {
                const float* base = fmap + (size_t)cc*HW;
                f2v d0 = *(const uf2*)(base + off0);
                f2v d1 = *(const uf2*)(base + off1);
                float v00 = xhi[ix] ? d0.y : d0.x;
                float v10 = xhi[ix] ? d1.y : d1.x;
                float r0 = v00 + lx[ix]*(d0.y - v00);
                float r1 = v10 + lx[ix]*(d1.y - v10);
                acc[cc] += hy[iy]*r0 + ly[iy]*r1;
            }
        }
    size_t obase = ((size_t)k*C + (size_t)c2*NC)*BINS + bin;
    #pragma unroll
    for (int cc=0; cc<NC; ++cc)
        out[obase + (size_t)cc*BINS] = acc[cc]*(1.0f/(SR*SR));
}

extern "C" void kernel_launch(void* const* d_in, const int* in_sizes, int n_in,
                              void* d_out, int out_size, void* d_ws, size_t ws_size,
                              hipStream_t stream) {
    const float* feat = (const float*)d_in[0];
    const float* rois = (const float*)d_in[1];
    float* out = (float*)d_out;

    const int C = 256, H = 200, W = 200;
    const int HW = H * W;
    const int K = in_sizes[1] / 5;
    const int N = in_sizes[0] / (C * HW);

    size_t need = (size_t)N * HW * CH * sizeof(u16);   // 82 MB for N=4
    if (ws_size >= need && (HW % 64) == 0) {
        const int tiles = HW / 64;                     // 625
        nchw_to_nhwc_bf16<<<N * tiles, 256, 0, stream>>>(feat, (u16*)d_ws, HW, tiles);
        roi_gather_nhwc<<<K * 4, 256, 0, stream>>>((const u16*)d_ws, rois, out, H, W, K);
    } else {
        const int threads_per_slice = K * BINS;
        const int block = 256;
        const int blocks_per_slice = (threads_per_slice + block - 1) / block;
        const int slices = C / NC;
        const int slices_per_xcd = slices / NXCD;
        const int grid = slices * blocks_per_slice;
        roi_align_fallback<<<grid, block, 0, stream>>>(feat, rois, out, C, H, W, K,
                                                       blocks_per_slice, slices_per_xcd);
    }
}

// Round 5
// 111.446 us; speedup vs baseline: 2.3437x; 1.0623x over previous
//
#include <hip/hip_runtime.h>

#define POOL_H 7
#define POOL_W 7
#define BINS   49
#define SR 2
#define SCALE 0.25f
#define CH 256          // channels (fixed by problem)

typedef unsigned int   u32;
typedef unsigned short u16;
typedef unsigned long long u64;
typedef float f2v __attribute__((ext_vector_type(2)));
typedef f2v uf2 __attribute__((aligned(4)));
typedef float f4  __attribute__((ext_vector_type(4)));
typedef u16  us4 __attribute__((ext_vector_type(4)));
typedef u32  ui2 __attribute__((ext_vector_type(2)));

__device__ __forceinline__ u16 f32_to_bf16_rne(float f) {
    u32 u = __builtin_bit_cast(u32, f);
    u32 r = (u + 0x7FFFu + ((u >> 16) & 1u)) >> 16;
    return (u16)r;
}
__device__ __forceinline__ float bf16lo(u32 u) { return __builtin_bit_cast(float, u << 16); }
__device__ __forceinline__ float bf16hi(u32 u) { return __builtin_bit_cast(float, u & 0xFFFF0000u); }

// ---------------- Pass 1: NCHW f32 -> NHWC bf16 transpose + ROI spatial sort
// Blocks [0, N*tiles): 64-hw x 256-ch transpose tile.
// Block  N*tiles (last): bitonic-sorts the K ROIs by (batch, morton(tile))
// so spatially-overlapping ROIs are adjacent in perm[] -> L2 reuse in pass 2.
// The single sort block (~5us) hides under the 2500 transpose blocks.
__global__ __launch_bounds__(256) void nchw_to_nhwc_bf16(
    const float* __restrict__ feat, u16* __restrict__ ft,
    const float* __restrict__ rois, int* __restrict__ perm,
    int HW, int tiles, int K, int H, int W)
{
    __shared__ __align__(16) unsigned char smem[64 * 260 * 2];  // 33 KB

    if ((int)blockIdx.x == gridDim.x - 1) {
        // ---- ROI spatial sort (K <= 1024) ----
        u64* keys = (u64*)smem;
        int t = threadIdx.x;
        for (int v = t; v < 1024; v += 256) {
            u64 kv = ~0ull;
            if (v < K) {
                const float* rp = rois + (size_t)v * 5;
                int b = (int)rp[0];
                float cx = 0.5f * (rp[1] + rp[3]) * SCALE;   // 0..W
                float cy = 0.5f * (rp[2] + rp[4]) * SCALE;   // 0..H
                int qx = min(7, max(0, (int)(cx * (8.0f / (float)W))));
                int qy = min(7, max(0, (int)(cy * (8.0f / (float)H))));
                u32 m = 0;
                #pragma unroll
                for (int i = 0; i < 3; ++i)
                    m |= (((qy >> i) & 1u) << (2 * i + 1)) | (((qx >> i) & 1u) << (2 * i));
                u32 key = ((u32)b << 6) | m;
                kv = ((u64)key << 32) | (u32)v;
            }
            keys[v] = kv;
        }
        __syncthreads();
        for (int size = 2; size <= 1024; size <<= 1) {
            for (int stride = size >> 1; stride > 0; stride >>= 1) {
                for (int v = t; v < 1024; v += 256) {
                    int j = v ^ stride;
                    if (j > v) {
                        bool up = ((v & size) == 0);
                        u64 a = keys[v], bb = keys[j];
                        if ((a > bb) == up) { keys[v] = bb; keys[j] = a; }
                    }
                }
                __syncthreads();
            }
        }
        for (int v = t; v < K; v += 256)
            perm[v] = (int)(keys[v] & 0xffffffffu);
        return;
    }

    // ---- transpose tile ----
    u16 (*lds)[260] = (u16 (*)[260])smem;   // +4 pad: 2-way bank alias (free)
    int b    = blockIdx.x / tiles;
    int tile = blockIdx.x % tiles;
    int hw0  = tile * 64;

    int lane = threadIdx.x & 63;
    int w    = threadIdx.x >> 6;

    const float* src = feat + (size_t)b * CH * HW;
    for (int c = w; c < CH; c += 4) {
        float v = src[(size_t)c * HW + hw0 + lane];
        lds[lane][c] = f32_to_bf16_rne(v);
    }
    __syncthreads();

    u16* dst = ft + ((size_t)b * HW + hw0) * CH;
    for (int it = 0; it < 8; ++it) {
        int id = it * 256 + (int)threadIdx.x;   // 16B chunk id, [0,2048)
        int r  = id >> 5;
        int o  = (id & 31) * 8;
        us4 lo = *(const us4*)&lds[r][o];
        us4 hi = *(const us4*)&lds[r][o + 4];
        *(us4*)(dst + (size_t)id * 8)     = lo;
        *(us4*)(dst + (size_t)id * 8 + 4) = hi;
    }
}

// ---------------- Pass 2: gather from NHWC bf16 -----------------------------
// slot = XCD-chunked block index: XCD g owns slots [g*chunk,(g+1)*chunk) so it
// sweeps spatially-sorted ROIs sequentially -> overlapping windows hit its L2.
__global__ __launch_bounds__(256) void roi_gather_nhwc(
    const u16* __restrict__ ft,      // [N][H][W][CH] bf16
    const float* __restrict__ rois,  // [K][5]
    const int* __restrict__ perm,    // [K] spatial order
    float* __restrict__ out,         // [K][CH][7][7]
    int H, int W, int K, int chunk, int do_swz)
{
    int bid  = blockIdx.x;
    int slot = do_swz ? (bid & 7) * chunk + (bid >> 3) : bid;
    int k    = perm[slot >> 2];
    int q    = slot & 3;
    int bin0 = q * 13;
    int nb   = min(BINS - bin0, 13);

    __shared__ float lds[13][CH];    // 13 KB -> 8 blocks/CU

    int lane = threadIdx.x & 63;
    int w    = threadIdx.x >> 6;

    const float* rp = rois + (size_t)k * 5;
    int   b   = (int)rp[0];
    float rx1 = rp[1] * SCALE - 0.5f;
    float ry1 = rp[2] * SCALE - 0.5f;
    float rx2 = rp[3] * SCALE - 0.5f;
    float ry2 = rp[4] * SCALE - 0.5f;
    float bin_h = (ry2 - ry1) * (1.0f / POOL_H);
    float bin_w = (rx2 - rx1) * (1.0f / POOL_W);

    const u16* fbase = ft + (size_t)b * H * W * CH + lane * 4;

    for (int lb = w; lb < nb; lb += 4) {
        int bin = bin0 + lb;
        int ph  = bin / 7;
        int pw  = bin % 7;

        float a0 = 0.f, a1 = 0.f, a2 = 0.f, a3 = 0.f;
        #pragma unroll
        for (int iy = 0; iy < SR; ++iy) {
            float y = ry1 + ((float)ph + ((float)iy + 0.5f) * (1.0f / SR)) * bin_h;
            bool vy = (y > -1.0f) && (y < (float)H);
            float yc = fminf(fmaxf(y, 0.0f), (float)(H - 1));
            int   y0 = (int)yc;
            int   y1 = min(y0 + 1, H - 1);
            float ly = yc - (float)y0;
            float hy = 1.0f - ly;
            #pragma unroll
            for (int ix = 0; ix < SR; ++ix) {
                float x = rx1 + ((float)pw + ((float)ix + 0.5f) * (1.0f / SR)) * bin_w;
                bool vx = (x > -1.0f) && (x < (float)W);
                if (!(vy && vx)) continue;       // wave-uniform branch
                float xc = fminf(fmaxf(x, 0.0f), (float)(W - 1));
                int   x0 = (int)xc;
                int   x1 = min(x0 + 1, W - 1);
                float lx = xc - (float)x0;
                float hx = 1.0f - lx;

                float w00 = hy * hx, w01 = hy * lx, w10 = ly * hx, w11 = ly * lx;
                int p00 = y0 * W + x0, p01 = y0 * W + x1;
                int p10 = y1 * W + x0, p11 = y1 * W + x1;

                #define CORNER(P, WT) {                                   \
                    ui2 u = *(const ui2*)(fbase + (size_t)(P) * CH);      \
                    a0 += (WT) * bf16lo(u.x);  a1 += (WT) * bf16hi(u.x);  \
                    a2 += (WT) * bf16lo(u.y);  a3 += (WT) * bf16hi(u.y);  \
                }
                CORNER(p00, w00); CORNER(p01, w01);
                CORNER(p10, w10); CORNER(p11, w11);
                #undef CORNER
            }
        }
        f4 res = { a0 * 0.25f, a1 * 0.25f, a2 * 0.25f, a3 * 0.25f };
        *(f4*)&lds[lb][lane * 4] = res;
    }
    __syncthreads();

    float* ob = out + (size_t)k * CH * BINS + bin0;
    for (int id = (int)threadIdx.x; id < 13 * CH; id += 256) {
        int c  = id / 13;
        int lb = id % 13;
        if (lb < nb) ob[(size_t)c * BINS + lb] = lds[lb][c];
    }
}

// ---------------- Fallback (round-3 kernel) if ws too small -----------------
#define NC 2
#define NXCD 8
__global__ __launch_bounds__(256) void roi_align_fallback(
    const float* __restrict__ feat, const float* __restrict__ rois,
    float* __restrict__ out, int C, int H, int W, int K,
    int blocks_per_slice, int slices_per_xcd)
{
    int wgid  = blockIdx.x;
    int g     = wgid % NXCD;
    int r     = wgid / NXCD;
    int slice = g * slices_per_xcd + r / blocks_per_slice;
    int j     = r % blocks_per_slice;
    int tid = j * (int)blockDim.x + (int)threadIdx.x;
    int k   = tid / BINS;
    int bin = tid % BINS;
    if (k >= K) return;
    int pw = bin % POOL_W, ph = bin / POOL_W, c2 = slice;

    const float* rp = rois + (size_t)k * 5;
    int b = (int)rp[0];
    float rx1 = rp[1]*SCALE-0.5f, ry1 = rp[2]*SCALE-0.5f;
    float rx2 = rp[3]*SCALE-0.5f, ry2 = rp[4]*SCALE-0.5f;
    float bin_h = (ry2-ry1)*(1.0f/POOL_H), bin_w = (rx2-rx1)*(1.0f/POOL_W);

    int yr0[SR], yr1[SR]; float ly[SR], hy[SR]; bool vy[SR];
    #pragma unroll
    for (int iy = 0; iy < SR; ++iy) {
        float y = ry1 + ((float)ph + ((float)iy+0.5f)*(1.0f/SR))*bin_h;
        vy[iy] = (y > -1.0f) && (y < (float)H);
        float yc = fminf(fmaxf(y, 0.0f), (float)(H-1));
        int y0 = (int)yc; yr0[iy]=y0; yr1[iy]=min(y0+1,H-1);
        ly[iy]=yc-(float)y0; hy[iy]=1.0f-ly[iy];
    }
    int xl[SR]; float lx[SR]; bool vx[SR], xhi[SR];
    #pragma unroll
    for (int ix = 0; ix < SR; ++ix) {
        float x = rx1 + ((float)pw + ((float)ix+0.5f)*(1.0f/SR))*bin_w;
        vx[ix] = (x > -1.0f) && (x < (float)W);
        float xc = fminf(fmaxf(x, 0.0f), (float)(W-1));
        int x0 = (int)xc; int xload = min(x0, W-2);
        xl[ix]=xload; xhi[ix]=(x0>xload); lx[ix]=xc-(float)x0;
    }
    const size_t HW = (size_t)H*W;
    const float* fmap = feat + ((size_t)b*C + (size_t)c2*NC)*HW;
    float acc[NC];
    #pragma unroll
    for (int cc=0; cc<NC; ++cc) acc[cc]=0.0f;
    #pragma unroll
    for (int iy=0; iy<SR; ++iy)
      #pragma unroll
      for (int ix=0; ix<SR; ++ix)
        if (vy[iy] && vx[ix]) {
            int off0 = yr0[iy]*W + xl[ix], off1 = yr1[iy]*W + xl[ix];
            #pragma unroll
            for (int cc=0; cc<NC; ++cc) {
                const float* base = fmap + (size_t)cc*HW;
                f2v d0 = *(const uf2*)(base + off0);
                f2v d1 = *(const uf2*)(base + off1);
                float v00 = xhi[ix] ? d0.y : d0.x;
                float v10 = xhi[ix] ? d1.y : d1.x;
                float r0 = v00 + lx[ix]*(d0.y - v00);
                float r1 = v10 + lx[ix]*(d1.y - v10);
                acc[cc] += hy[iy]*r0 + ly[iy]*r1;
            }
        }
    size_t obase = ((size_t)k*C + (size_t)c2*NC)*BINS + bin;
    #pragma unroll
    for (int cc=0; cc<NC; ++cc)
        out[obase + (size_t)cc*BINS] = acc[cc]*(1.0f/(SR*SR));
}

extern "C" void kernel_launch(void* const* d_in, const int* in_sizes, int n_in,
                              void* d_out, int out_size, void* d_ws, size_t ws_size,
                              hipStream_t stream) {
    const float* feat = (const float*)d_in[0];
    const float* rois = (const float*)d_in[1];
    float* out = (float*)d_out;

    const int C = 256, H = 200, W = 200;
    const int HW = H * W;
    const int K = in_sizes[1] / 5;
    const int N = in_sizes[0] / (C * HW);

    size_t nhwc_bytes = (size_t)N * HW * CH * sizeof(u16);   // 82 MB for N=4
    size_t need = nhwc_bytes + (size_t)K * sizeof(int);
    if (ws_size >= need && (HW % 64) == 0 && K <= 1024) {
        u16* ft   = (u16*)d_ws;
        int* perm = (int*)((char*)d_ws + nhwc_bytes);
        const int tiles = HW / 64;                           // 625
        nchw_to_nhwc_bf16<<<N * tiles + 1, 256, 0, stream>>>(
            feat, ft, rois, perm, HW, tiles, K, H, W);
        int grid  = K * 4;
        int swz   = (grid % 8) == 0;
        int chunk = grid / 8;
        roi_gather_nhwc<<<grid, 256, 0, stream>>>(
            (const u16*)ft, rois, perm, out, H, W, K, chunk, swz);
    } else {
        const int threads_per_slice = K * BINS;
        const int block = 256;
        const int blocks_per_slice = (threads_per_slice + block - 1) / block;
        const int slices = C / NC;
        const int slices_per_xcd = slices / NXCD;
        const int grid = slices * blocks_per_slice;
        roi_align_fallback<<<grid, block, 0, stream>>>(feat, rois, out, C, H, W, K,
                                                       blocks_per_slice, slices_per_xcd);
    }
}

// Round 6
// 110.814 us; speedup vs baseline: 2.3570x; 1.0057x over previous
//
#include <hip/hip_runtime.h>

#define POOL_H 7
#define POOL_W 7
#define BINS   49
#define SR 2
#define SCALE 0.25f
#define CH 256          // channels (fixed by problem)

typedef unsigned int   u32;
typedef unsigned short u16;
typedef unsigned long long u64;
typedef float f2v __attribute__((ext_vector_type(2)));
typedef f2v uf2 __attribute__((aligned(4)));
typedef float f4  __attribute__((ext_vector_type(4)));
typedef u16  us4 __attribute__((ext_vector_type(4)));
typedef u32  ui2 __attribute__((ext_vector_type(2)));

__device__ __forceinline__ u16 f32_to_bf16_rne(float f) {
    u32 u = __builtin_bit_cast(u32, f);
    u32 r = (u + 0x7FFFu + ((u >> 16) & 1u)) >> 16;
    return (u16)r;
}
__device__ __forceinline__ float bf16lo(u32 u) { return __builtin_bit_cast(float, u << 16); }
__device__ __forceinline__ float bf16hi(u32 u) { return __builtin_bit_cast(float, u & 0xFFFF0000u); }

// ---------------- Pass 1: NCHW f32 -> NHWC bf16 transpose + ROI spatial sort
// Blocks [0, N*tiles): 64-hw x 256-ch transpose tile.
// Last block: bitonic-sort K ROIs by (batch, morton16x16(center)) -> perm[].
__global__ __launch_bounds__(256) void nchw_to_nhwc_bf16(
    const float* __restrict__ feat, u16* __restrict__ ft,
    const float* __restrict__ rois, int* __restrict__ perm,
    int HW, int tiles, int K, int H, int W)
{
    __shared__ __align__(16) unsigned char smem[64 * 260 * 2];  // 33 KB

    if ((int)blockIdx.x == gridDim.x - 1) {
        u64* keys = (u64*)smem;
        int t = threadIdx.x;
        for (int v = t; v < 1024; v += 256) {
            u64 kv = ~0ull;
            if (v < K) {
                const float* rp = rois + (size_t)v * 5;
                int b = (int)rp[0];
                float cx = 0.5f * (rp[1] + rp[3]) * SCALE;   // 0..W
                float cy = 0.5f * (rp[2] + rp[4]) * SCALE;   // 0..H
                int qx = min(15, max(0, (int)(cx * (16.0f / (float)W))));
                int qy = min(15, max(0, (int)(cy * (16.0f / (float)H))));
                u32 m = 0;
                #pragma unroll
                for (int i = 0; i < 4; ++i)
                    m |= (((qy >> i) & 1u) << (2 * i + 1)) | (((qx >> i) & 1u) << (2 * i));
                u32 key = ((u32)b << 8) | m;
                kv = ((u64)key << 32) | (u32)v;
            }
            keys[v] = kv;
        }
        __syncthreads();
        for (int size = 2; size <= 1024; size <<= 1) {
            for (int stride = size >> 1; stride > 0; stride >>= 1) {
                for (int v = t; v < 1024; v += 256) {
                    int j = v ^ stride;
                    if (j > v) {
                        bool up = ((v & size) == 0);
                        u64 a = keys[v], bb = keys[j];
                        if ((a > bb) == up) { keys[v] = bb; keys[j] = a; }
                    }
                }
                __syncthreads();
            }
        }
        for (int v = t; v < K; v += 256)
            perm[v] = (int)(keys[v] & 0xffffffffu);
        return;
    }

    u16 (*lds)[260] = (u16 (*)[260])smem;
    int b    = blockIdx.x / tiles;
    int tile = blockIdx.x % tiles;
    int hw0  = tile * 64;

    int lane = threadIdx.x & 63;
    int w    = threadIdx.x >> 6;

    const float* src = feat + (size_t)b * CH * HW;
    for (int c = w; c < CH; c += 4) {
        float v = src[(size_t)c * HW + hw0 + lane];
        lds[lane][c] = f32_to_bf16_rne(v);
    }
    __syncthreads();

    u16* dst = ft + ((size_t)b * HW + hw0) * CH;
    for (int it = 0; it < 8; ++it) {
        int id = it * 256 + (int)threadIdx.x;
        int r  = id >> 5;
        int o  = (id & 31) * 8;
        us4 lo = *(const us4*)&lds[r][o];
        us4 hi = *(const us4*)&lds[r][o + 4];
        *(us4*)(dst + (size_t)id * 8)     = lo;
        *(us4*)(dst + (size_t)id * 8 + 4) = hi;
    }
}

// ---------------- Pass 2: gather from NHWC bf16 -----------------------------
// 7 blocks per ROI (one pooled row each), 448 threads = 7 waves = 1 bin/wave.
// Only ~4 blocks/CU resident -> ~18 ROIs in flight per XCD (~1.2 MB window)
// << 4 MB L2, so sorted-ROI overlap is served by the XCD's private L2.
__global__ __launch_bounds__(448) void roi_gather_nhwc(
    const u16* __restrict__ ft,      // [N][H][W][CH] bf16
    const float* __restrict__ rois,  // [K][5]
    const int* __restrict__ perm,    // [K] spatial order
    float* __restrict__ out,         // [K][CH][7][7]
    int H, int W, int K, int chunk, int do_swz)
{
    int bid  = blockIdx.x;
    int slot = do_swz ? (bid & 7) * chunk + (bid >> 3) : bid;
    int k    = perm[slot / 7];
    int q    = slot % 7;             // pooled row ph == q
    int bin0 = q * 7;

    __shared__ float lds[7][CH];     // 7 KB

    int lane = threadIdx.x & 63;
    int w    = threadIdx.x >> 6;     // wave = bin index within row, 0..6

    const float* rp = rois + (size_t)k * 5;
    int   b   = (int)rp[0];
    float rx1 = rp[1] * SCALE - 0.5f;
    float ry1 = rp[2] * SCALE - 0.5f;
    float rx2 = rp[3] * SCALE - 0.5f;
    float ry2 = rp[4] * SCALE - 0.5f;
    float bin_h = (ry2 - ry1) * (1.0f / POOL_H);
    float bin_w = (rx2 - rx1) * (1.0f / POOL_W);

    const u16* fbase = ft + (size_t)b * H * W * CH + lane * 4;

    {
        int ph = q;
        int pw = w;

        float a0 = 0.f, a1 = 0.f, a2 = 0.f, a3 = 0.f;
        #pragma unroll
        for (int iy = 0; iy < SR; ++iy) {
            float y = ry1 + ((float)ph + ((float)iy + 0.5f) * (1.0f / SR)) * bin_h;
            bool vy = (y > -1.0f) && (y < (float)H);
            float yc = fminf(fmaxf(y, 0.0f), (float)(H - 1));
            int   y0 = (int)yc;
            int   y1 = min(y0 + 1, H - 1);
            float ly = yc - (float)y0;
            float hy = 1.0f - ly;
            #pragma unroll
            for (int ix = 0; ix < SR; ++ix) {
                float x = rx1 + ((float)pw + ((float)ix + 0.5f) * (1.0f / SR)) * bin_w;
                bool vx = (x > -1.0f) && (x < (float)W);
                if (!(vy && vx)) continue;       // wave-uniform branch
                float xc = fminf(fmaxf(x, 0.0f), (float)(W - 1));
                int   x0 = (int)xc;
                int   x1 = min(x0 + 1, W - 1);
                float lx = xc - (float)x0;
                float hx = 1.0f - lx;

                float w00 = hy * hx, w01 = hy * lx, w10 = ly * hx, w11 = ly * lx;
                int p00 = y0 * W + x0, p01 = y0 * W + x1;
                int p10 = y1 * W + x0, p11 = y1 * W + x1;

                #define CORNER(P, WT) {                                   \
                    ui2 u = *(const ui2*)(fbase + (size_t)(P) * CH);      \
                    a0 += (WT) * bf16lo(u.x);  a1 += (WT) * bf16hi(u.x);  \
                    a2 += (WT) * bf16lo(u.y);  a3 += (WT) * bf16hi(u.y);  \
                }
                CORNER(p00, w00); CORNER(p01, w01);
                CORNER(p10, w10); CORNER(p11, w11);
                #undef CORNER
            }
        }
        f4 res = { a0 * 0.25f, a1 * 0.25f, a2 * 0.25f, a3 * 0.25f };
        *(f4*)&lds[w][lane * 4] = res;
    }
    __syncthreads();

    // out[k][c][bin0 + lb]: 7-float contiguous runs per channel
    float* ob = out + (size_t)k * CH * BINS + bin0;
    for (int id = (int)threadIdx.x; id < 7 * CH; id += 448) {
        int c  = id / 7;
        int lb = id % 7;
        ob[(size_t)c * BINS + lb] = lds[lb][c];
    }
}

// ---------------- Fallback (round-3 kernel) if ws too small -----------------
#define NC 2
#define NXCD 8
__global__ __launch_bounds__(256) void roi_align_fallback(
    const float* __restrict__ feat, const float* __restrict__ rois,
    float* __restrict__ out, int C, int H, int W, int K,
    int blocks_per_slice, int slices_per_xcd)
{
    int wgid  = blockIdx.x;
    int g     = wgid % NXCD;
    int r     = wgid / NXCD;
    int slice = g * slices_per_xcd + r / blocks_per_slice;
    int j     = r % blocks_per_slice;
    int tid = j * (int)blockDim.x + (int)threadIdx.x;
    int k   = tid / BINS;
    int bin = tid % BINS;
    if (k >= K) return;
    int pw = bin % POOL_W, ph = bin / POOL_W, c2 = slice;

    const float* rp = rois + (size_t)k * 5;
    int b = (int)rp[0];
    float rx1 = rp[1]*SCALE-0.5f, ry1 = rp[2]*SCALE-0.5f;
    float rx2 = rp[3]*SCALE-0.5f, ry2 = rp[4]*SCALE-0.5f;
    float bin_h = (ry2-ry1)*(1.0f/POOL_H), bin_w = (rx2-rx1)*(1.0f/POOL_W);

    int yr0[SR], yr1[SR]; float ly[SR], hy[SR]; bool vy[SR];
    #pragma unroll
    for (int iy = 0; iy < SR; ++iy) {
        float y = ry1 + ((float)ph + ((float)iy+0.5f)*(1.0f/SR))*bin_h;
        vy[iy] = (y > -1.0f) && (y < (float)H);
        float yc = fminf(fmaxf(y, 0.0f), (float)(H-1));
        int y0 = (int)yc; yr0[iy]=y0; yr1[iy]=min(y0+1,H-1);
        ly[iy]=yc-(float)y0; hy[iy]=1.0f-ly[iy];
    }
    int xl[SR]; float lx[SR]; bool vx[SR], xhi[SR];
    #pragma unroll
    for (int ix = 0; ix < SR; ++ix) {
        float x = rx1 + ((float)pw + ((float)ix+0.5f)*(1.0f/SR))*bin_w;
        vx[ix] = (x > -1.0f) && (x < (float)W);
        float xc = fminf(fmaxf(x, 0.0f), (float)(W-1));
        int x0 = (int)xc; int xload = min(x0, W-2);
        xl[ix]=xload; xhi[ix]=(x0>xload); lx[ix]=xc-(float)x0;
    }
    const size_t HW = (size_t)H*W;
    const float* fmap = feat + ((size_t)b*C + (size_t)c2*NC)*HW;
    float acc[NC];
    #pragma unroll
    for (int cc=0; cc<NC; ++cc) acc[cc]=0.0f;
    #pragma unroll
    for (int iy=0; iy<SR; ++iy)
      #pragma unroll
      for (int ix=0; ix<SR; ++ix)
        if (vy[iy] && vx[ix]) {
            int off0 = yr0[iy]*W + xl[ix], off1 = yr1[iy]*W + xl[ix];
            #pragma unroll
            for (int cc=0; cc<NC; ++cc) {
                const float* base = fmap + (size_t)cc*HW;
                f2v d0 = *(const uf2*)(base + off0);
                f2v d1 = *(const uf2*)(base + off1);
                float v00 = xhi[ix] ? d0.y : d0.x;
                float v10 = xhi[ix] ? d1.y : d1.x;
                float r0 = v00 + lx[ix]*(d0.y - v00);
                float r1 = v10 + lx[ix]*(d1.y - v10);
                acc[cc] += hy[iy]*r0 + ly[iy]*r1;
            }
        }
    size_t obase = ((size_t)k*C + (size_t)c2*NC)*BINS + bin;
    #pragma unroll
    for (int cc=0; cc<NC; ++cc)
        out[obase + (size_t)cc*BINS] = acc[cc]*(1.0f/(SR*SR));
}

extern "C" void kernel_launch(void* const* d_in, const int* in_sizes, int n_in,
                              void* d_out, int out_size, void* d_ws, size_t ws_size,
                              hipStream_t stream) {
    const float* feat = (const float*)d_in[0];
    const float* rois = (const float*)d_in[1];
    float* out = (float*)d_out;

    const int C = 256, H = 200, W = 200;
    const int HW = H * W;
    const int K = in_sizes[1] / 5;
    const int N = in_sizes[0] / (C * HW);

    size_t nhwc_bytes = (size_t)N * HW * CH * sizeof(u16);   // 82 MB for N=4
    size_t need = nhwc_bytes + (size_t)K * sizeof(int);
    if (ws_size >= need && (HW % 64) == 0 && K <= 1024) {
        u16* ft   = (u16*)d_ws;
        int* perm = (int*)((char*)d_ws + nhwc_bytes);
        const int tiles = HW / 64;                           // 625
        nchw_to_nhwc_bf16<<<N * tiles + 1, 256, 0, stream>>>(
            feat, ft, rois, perm, HW, tiles, K, H, W);
        int grid  = K * 7;                                   // 7168 for K=1024
        int swz   = (grid % 8) == 0;
        int chunk = grid / 8;
        roi_gather_nhwc<<<grid, 448, 0, stream>>>(
            (const u16*)ft, rois, perm, out, H, W, K, chunk, swz);
    } else {
        const int threads_per_slice = K * BINS;
        const int block = 256;
        const int blocks_per_slice = (threads_per_slice + block - 1) / block;
        const int slices = C / NC;
        const int slices_per_xcd = slices / NXCD;
        const int grid = slices * blocks_per_slice;
        roi_align_fallback<<<grid, block, 0, stream>>>(feat, rois, out, C, H, W, K,
                                                       blocks_per_slice, slices_per_xcd);
    }
}

// Round 7
// 107.892 us; speedup vs baseline: 2.4209x; 1.0271x over previous
//
#include <hip/hip_runtime.h>

#define POOL_H 7
#define POOL_W 7
#define BINS   49
#define SR 2
#define SCALE 0.25f
#define CH 256          // channels (fixed by problem)

typedef unsigned int   u32;
typedef unsigned short u16;
typedef unsigned long long u64;
typedef float f2v __attribute__((ext_vector_type(2)));
typedef f2v uf2 __attribute__((aligned(4)));
typedef float f4  __attribute__((ext_vector_type(4)));
typedef u16  us4 __attribute__((ext_vector_type(4)));
typedef u32  ui4 __attribute__((ext_vector_type(4)));

__device__ __forceinline__ u16 f32_to_bf16_rne(float f) {
    u32 u = __builtin_bit_cast(u32, f);
    u32 r = (u + 0x7FFFu + ((u >> 16) & 1u)) >> 16;
    return (u16)r;
}
__device__ __forceinline__ float bf16lo(u32 u) { return __builtin_bit_cast(float, u << 16); }
__device__ __forceinline__ float bf16hi(u32 u) { return __builtin_bit_cast(float, u & 0xFFFF0000u); }

// ---------------- Pass 1: NCHW f32 -> NHWC bf16 transpose + ROI spatial sort
__global__ __launch_bounds__(256) void nchw_to_nhwc_bf16(
    const float* __restrict__ feat, u16* __restrict__ ft,
    const float* __restrict__ rois, int* __restrict__ perm,
    int HW, int tiles, int K, int H, int W)
{
    __shared__ __align__(16) unsigned char smem[64 * 260 * 2];  // 33 KB

    if ((int)blockIdx.x == gridDim.x - 1) {
        u64* keys = (u64*)smem;
        int t = threadIdx.x;
        for (int v = t; v < 1024; v += 256) {
            u64 kv = ~0ull;
            if (v < K) {
                const float* rp = rois + (size_t)v * 5;
                int b = (int)rp[0];
                float cx = 0.5f * (rp[1] + rp[3]) * SCALE;
                float cy = 0.5f * (rp[2] + rp[4]) * SCALE;
                int qx = min(15, max(0, (int)(cx * (16.0f / (float)W))));
                int qy = min(15, max(0, (int)(cy * (16.0f / (float)H))));
                u32 m = 0;
                #pragma unroll
                for (int i = 0; i < 4; ++i)
                    m |= (((qy >> i) & 1u) << (2 * i + 1)) | (((qx >> i) & 1u) << (2 * i));
                u32 key = ((u32)b << 8) | m;
                kv = ((u64)key << 32) | (u32)v;
            }
            keys[v] = kv;
        }
        __syncthreads();
        for (int size = 2; size <= 1024; size <<= 1) {
            for (int stride = size >> 1; stride > 0; stride >>= 1) {
                for (int v = t; v < 1024; v += 256) {
                    int j = v ^ stride;
                    if (j > v) {
                        bool up = ((v & size) == 0);
                        u64 a = keys[v], bb = keys[j];
                        if ((a > bb) == up) { keys[v] = bb; keys[j] = a; }
                    }
                }
                __syncthreads();
            }
        }
        for (int v = t; v < K; v += 256)
            perm[v] = (int)(keys[v] & 0xffffffffu);
        return;
    }

    u16 (*lds)[260] = (u16 (*)[260])smem;
    int b    = blockIdx.x / tiles;
    int tile = blockIdx.x % tiles;
    int hw0  = tile * 64;

    int lane = threadIdx.x & 63;
    int w    = threadIdx.x >> 6;

    const float* src = feat + (size_t)b * CH * HW;
    for (int c = w; c < CH; c += 4) {
        float v = src[(size_t)c * HW + hw0 + lane];
        lds[lane][c] = f32_to_bf16_rne(v);
    }
    __syncthreads();

    u16* dst = ft + ((size_t)b * HW + hw0) * CH;
    for (int it = 0; it < 8; ++it) {
        int id = it * 256 + (int)threadIdx.x;
        int r  = id >> 5;
        int o  = (id & 31) * 8;
        us4 lo = *(const us4*)&lds[r][o];
        us4 hi = *(const us4*)&lds[r][o + 4];
        *(us4*)(dst + (size_t)id * 8)     = lo;
        *(us4*)(dst + (size_t)id * 8 + 4) = hi;
    }
}

// ---------------- Pass 2: gather from NHWC bf16 (row-split waves) -----------
// Wave = one bin. Lanes 0-31 own the y0 sample row, lanes 32-63 the y1 row;
// each lane carries 8 channels (16B dwordx4/load). Per sample: 2 gather
// instructions (corner column x0 for both rows; corner column x1). Per bin:
// 8 VMEM (vs 16 before) at 16B/lane. Row halves combined once per bin via
// shfl_xor(32).
__global__ __launch_bounds__(448) void roi_gather_nhwc(
    const u16* __restrict__ ft,      // [N][H][W][CH] bf16
    const float* __restrict__ rois,  // [K][5]
    const int* __restrict__ perm,    // [K] spatial order
    float* __restrict__ out,         // [K][CH][7][7]
    int H, int W, int K, int chunk, int do_swz)
{
    int bid  = blockIdx.x;
    int slot = do_swz ? (bid & 7) * chunk + (bid >> 3) : bid;
    int k    = perm[slot / 7];
    int q    = slot % 7;             // pooled row ph == q
    int bin0 = q * 7;

    __shared__ float lds[7][CH];     // 7 KB

    int lane = threadIdx.x & 63;
    int w    = threadIdx.x >> 6;     // wave = pw (bin col), 0..6
    int half = lane >> 5;            // 0: y0 row, 1: y1 row
    int lc   = lane & 31;            // channel group: ch 8*lc .. 8*lc+7

    const float* rp = rois + (size_t)k * 5;
    int   b   = (int)rp[0];
    float rx1 = rp[1] * SCALE - 0.5f;
    float ry1 = rp[2] * SCALE - 0.5f;
    float rx2 = rp[3] * SCALE - 0.5f;
    float ry2 = rp[4] * SCALE - 0.5f;
    float bin_h = (ry2 - ry1) * (1.0f / POOL_H);
    float bin_w = (rx2 - rx1) * (1.0f / POOL_W);

    const u16* fbase = ft + (size_t)b * H * W * CH + lc * 8;

    int ph = q;
    int pw = w;

    float acc[8];
    #pragma unroll
    for (int j = 0; j < 8; ++j) acc[j] = 0.0f;

    #pragma unroll
    for (int iy = 0; iy < SR; ++iy) {
        float y = ry1 + ((float)ph + ((float)iy + 0.5f) * (1.0f / SR)) * bin_h;
        bool vy = (y > -1.0f) && (y < (float)H);
        float yc = fminf(fmaxf(y, 0.0f), (float)(H - 1));
        int   y0 = (int)yc;
        int   y1 = min(y0 + 1, H - 1);
        float ly = yc - (float)y0;
        float hy = 1.0f - ly;
        int   ysel = half ? y1 : y0;       // per-lane row select (cndmask)
        float wrow = half ? ly : hy;       // per-lane row weight
        #pragma unroll
        for (int ix = 0; ix < SR; ++ix) {
            float x = rx1 + ((float)pw + ((float)ix + 0.5f) * (1.0f / SR)) * bin_w;
            bool vx = (x > -1.0f) && (x < (float)W);
            if (!(vy && vx)) continue;     // wave-uniform branch
            float xc = fminf(fmaxf(x, 0.0f), (float)(W - 1));
            int   x0 = (int)xc;
            int   x1 = min(x0 + 1, W - 1);
            float lx = xc - (float)x0;

            const u16* p0 = fbase + (size_t)(ysel * W + x0) * CH;
            ui4 A = *(const ui4*)p0;                               // (row, x0) 8ch
            ui4 B = *(const ui4*)(p0 + (size_t)(x1 - x0) * CH);    // (row, x1) 8ch

            #pragma unroll
            for (int j = 0; j < 4; ++j) {
                float a0 = bf16lo(A[j]), a1 = bf16hi(A[j]);
                float b0 = bf16lo(B[j]), b1 = bf16hi(B[j]);
                float r0 = a0 + lx * (b0 - a0);
                float r1 = a1 + lx * (b1 - a1);
                acc[2 * j]     += wrow * r0;
                acc[2 * j + 1] += wrow * r1;
            }
        }
    }

    // combine row halves: lane l gets lane l^32's partial
    #pragma unroll
    for (int j = 0; j < 8; ++j)
        acc[j] = (acc[j] + __shfl_xor(acc[j], 32, 64)) * 0.25f;

    if (half == 0) {
        f4 lo = { acc[0], acc[1], acc[2], acc[3] };
        f4 hi = { acc[4], acc[5], acc[6], acc[7] };
        *(f4*)&lds[w][lc * 8]     = lo;
        *(f4*)&lds[w][lc * 8 + 4] = hi;
    }
    __syncthreads();

    float* ob = out + (size_t)k * CH * BINS + bin0;
    for (int id = (int)threadIdx.x; id < 7 * CH; id += 448) {
        int c  = id / 7;
        int lb = id % 7;
        ob[(size_t)c * BINS + lb] = lds[lb][c];
    }
}

// ---------------- Fallback (round-3 kernel) if ws too small -----------------
#define NC 2
#define NXCD 8
__global__ __launch_bounds__(256) void roi_align_fallback(
    const float* __restrict__ feat, const float* __restrict__ rois,
    float* __restrict__ out, int C, int H, int W, int K,
    int blocks_per_slice, int slices_per_xcd)
{
    int wgid  = blockIdx.x;
    int g     = wgid % NXCD;
    int r     = wgid / NXCD;
    int slice = g * slices_per_xcd + r / blocks_per_slice;
    int j     = r % blocks_per_slice;
    int tid = j * (int)blockDim.x + (int)threadIdx.x;
    int k   = tid / BINS;
    int bin = tid % BINS;
    if (k >= K) return;
    int pw = bin % POOL_W, ph = bin / POOL_W, c2 = slice;

    const float* rp = rois + (size_t)k * 5;
    int b = (int)rp[0];
    float rx1 = rp[1]*SCALE-0.5f, ry1 = rp[2]*SCALE-0.5f;
    float rx2 = rp[3]*SCALE-0.5f, ry2 = rp[4]*SCALE-0.5f;
    float bin_h = (ry2-ry1)*(1.0f/POOL_H), bin_w = (rx2-rx1)*(1.0f/POOL_W);

    int yr0[SR], yr1[SR]; float ly[SR], hy[SR]; bool vy[SR];
    #pragma unroll
    for (int iy = 0; iy < SR; ++iy) {
        float y = ry1 + ((float)ph + ((float)iy+0.5f)*(1.0f/SR))*bin_h;
        vy[iy] = (y > -1.0f) && (y < (float)H);
        float yc = fminf(fmaxf(y, 0.0f), (float)(H-1));
        int y0 = (int)yc; yr0[iy]=y0; yr1[iy]=min(y0+1,H-1);
        ly[iy]=yc-(float)y0; hy[iy]=1.0f-ly[iy];
    }
    int xl[SR]; float lx[SR]; bool vx[SR], xhi[SR];
    #pragma unroll
    for (int ix = 0; ix < SR; ++ix) {
        float x = rx1 + ((float)pw + ((float)ix+0.5f)*(1.0f/SR))*bin_w;
        vx[ix] = (x > -1.0f) && (x < (float)W);
        float xc = fminf(fmaxf(x, 0.0f), (float)(W-1));
        int x0 = (int)xc; int xload = min(x0, W-2);
        xl[ix]=xload; xhi[ix]=(x0>xload); lx[ix]=xc-(float)x0;
    }
    const size_t HW = (size_t)H*W;
    const float* fmap = feat + ((size_t)b*C + (size_t)c2*NC)*HW;
    float acc[NC];
    #pragma unroll
    for (int cc=0; cc<NC; ++cc) acc[cc]=0.0f;
    #pragma unroll
    for (int iy=0; iy<SR; ++iy)
      #pragma unroll
      for (int ix=0; ix<SR; ++ix)
        if (vy[iy] && vx[ix]) {
            int off0 = yr0[iy]*W + xl[ix], off1 = yr1[iy]*W + xl[ix];
            #pragma unroll
            for (int cc=0; cc<NC; ++cc) {
                const float* base = fmap + (size_t)cc*HW;
                f2v d0 = *(const uf2*)(base + off0);
                f2v d1 = *(const uf2*)(base + off1);
                float v00 = xhi[ix] ? d0.y : d0.x;
                float v10 = xhi[ix] ? d1.y : d1.x;
                float r0 = v00 + lx[ix]*(d0.y - v00);
                float r1 = v10 + lx[ix]*(d1.y - v10);
                acc[cc] += hy[iy]*r0 + ly[iy]*r1;
            }
        }
    size_t obase = ((size_t)k*C + (size_t)c2*NC)*BINS + bin;
    #pragma unroll
    for (int cc=0; cc<NC; ++cc)
        out[obase + (size_t)cc*BINS] = acc[cc]*(1.0f/(SR*SR));
}

extern "C" void kernel_launch(void* const* d_in, const int* in_sizes, int n_in,
                              void* d_out, int out_size, void* d_ws, size_t ws_size,
                              hipStream_t stream) {
    const float* feat = (const float*)d_in[0];
    const float* rois = (const float*)d_in[1];
    float* out = (float*)d_out;

    const int C = 256, H = 200, W = 200;
    const int HW = H * W;
    const int K = in_sizes[1] / 5;
    const int N = in_sizes[0] / (C * HW);

    size_t nhwc_bytes = (size_t)N * HW * CH * sizeof(u16);   // 82 MB for N=4
    size_t need = nhwc_bytes + (size_t)K * sizeof(int);
    if (ws_size >= need && (HW % 64) == 0 && K <= 1024) {
        u16* ft   = (u16*)d_ws;
        int* perm = (int*)((char*)d_ws + nhwc_bytes);
        const int tiles = HW / 64;                           // 625
        nchw_to_nhwc_bf16<<<N * tiles + 1, 256, 0, stream>>>(
            feat, ft, rois, perm, HW, tiles, K, H, W);
        int grid  = K * 7;                                   // 7168 for K=1024
        int swz   = (grid % 8) == 0;
        int chunk = grid / 8;
        roi_gather_nhwc<<<grid, 448, 0, stream>>>(
            (const u16*)ft, rois, perm, out, H, W, K, chunk, swz);
    } else {
        const int threads_per_slice = K * BINS;
        const int block = 256;
        const int blocks_per_slice = (threads_per_slice + block - 1) / block;
        const int slices = C / NC;
        const int slices_per_xcd = slices / NXCD;
        const int grid = slices * blocks_per_slice;
        roi_align_fallback<<<grid, block, 0, stream>>>(feat, rois, out, C, H, W, K,
                                                       blocks_per_slice, slices_per_xcd);
    }
}

// Round 8
// 92.799 us; speedup vs baseline: 2.8146x; 1.1626x over previous
//
#include <hip/hip_runtime.h>

#define POOL_H 7
#define POOL_W 7
#define BINS   49
#define SR 2
#define SCALE 0.25f
#define CH 256          // channels (fixed by problem)

typedef unsigned int   u32;
typedef unsigned short u16;
typedef unsigned long long u64;
typedef float f2v __attribute__((ext_vector_type(2)));
typedef f2v uf2 __attribute__((aligned(4)));
typedef float f4  __attribute__((ext_vector_type(4)));
typedef u16  us4 __attribute__((ext_vector_type(4)));
typedef u32  ui2 __attribute__((ext_vector_type(2)));
typedef u32  ui4 __attribute__((ext_vector_type(4)));

__device__ __forceinline__ u16 f32_to_bf16_rne(float f) {
    u32 u = __builtin_bit_cast(u32, f);
    u32 r = (u + 0x7FFFu + ((u >> 16) & 1u)) >> 16;
    return (u16)r;
}
__device__ __forceinline__ float bf16lo(u32 u) { return __builtin_bit_cast(float, u << 16); }
__device__ __forceinline__ float bf16hi(u32 u) { return __builtin_bit_cast(float, u & 0xFFFF0000u); }

// ---------------- Pass 1: NCHW f32 -> NHWC bf16 transpose + ROI spatial sort
// 512 threads/block (8 waves): 4 blocks/CU x 8 waves = 32 waves/CU (was 31%
// occupancy). Read loop fully compile-time bounded + unrolled so >=4 global
// loads stay in flight per wave (was latency-serialized at ~1 load in flight).
__global__ __launch_bounds__(512) void nchw_to_nhwc_bf16(
    const float* __restrict__ feat, u16* __restrict__ ft,
    const float* __restrict__ rois, int* __restrict__ perm,
    int HW, int tiles, int K, int H, int W)
{
    __shared__ __align__(16) unsigned char smem[64 * 260 * 2];  // 33.3 KB

    int t = threadIdx.x;

    if ((int)blockIdx.x == gridDim.x - 1) {
        // ---- ROI spatial sort (K <= 1024) ----
        u64* keys = (u64*)smem;
        int bd = (int)blockDim.x;
        for (int v = t; v < 1024; v += bd) {
            u64 kv = ~0ull;
            if (v < K) {
                const float* rp = rois + (size_t)v * 5;
                int b = (int)rp[0];
                float cx = 0.5f * (rp[1] + rp[3]) * SCALE;
                float cy = 0.5f * (rp[2] + rp[4]) * SCALE;
                int qx = min(15, max(0, (int)(cx * (16.0f / (float)W))));
                int qy = min(15, max(0, (int)(cy * (16.0f / (float)H))));
                u32 m = 0;
                #pragma unroll
                for (int i = 0; i < 4; ++i)
                    m |= (((qy >> i) & 1u) << (2 * i + 1)) | (((qx >> i) & 1u) << (2 * i));
                u32 key = ((u32)b << 8) | m;
                kv = ((u64)key << 32) | (u32)v;
            }
            keys[v] = kv;
        }
        __syncthreads();
        for (int size = 2; size <= 1024; size <<= 1) {
            for (int stride = size >> 1; stride > 0; stride >>= 1) {
                for (int v = t; v < 1024; v += bd) {
                    int j = v ^ stride;
                    if (j > v) {
                        bool up = ((v & size) == 0);
                        u64 a = keys[v], bb = keys[j];
                        if ((a > bb) == up) { keys[v] = bb; keys[j] = a; }
                    }
                }
                __syncthreads();
            }
        }
        for (int v = t; v < K; v += bd)
            perm[v] = (int)(keys[v] & 0xffffffffu);
        return;
    }

    u16 (*lds)[260] = (u16 (*)[260])smem;
    int b    = blockIdx.x / tiles;
    int tile = blockIdx.x % tiles;
    int hw0  = tile * 64;

    int lane = t & 63;
    int w    = t >> 6;          // 0..7

    // Read: wave w covers c = w, w+8, ..., w+248. 256B coalesced per instr.
    const float* src = feat + (size_t)b * CH * HW + hw0 + lane;
    #pragma unroll 4
    for (int i = 0; i < 32; ++i) {
        int c = w + 8 * i;
        float v = src[(size_t)c * HW];
        lds[lane][c] = f32_to_bf16_rne(v);
    }
    __syncthreads();

    // Store: 2048 x 16B chunks; one dwordx4 per thread-iter (dense 1KB/wave).
    u16* dst = ft + ((size_t)b * HW + hw0) * CH;
    #pragma unroll
    for (int it = 0; it < 4; ++it) {
        int id = it * 512 + t;                  // [0,2048)
        int r  = id >> 5;
        int o  = (id & 31) * 8;
        ui2 lo = __builtin_bit_cast(ui2, *(const us4*)&lds[r][o]);
        ui2 hi = __builtin_bit_cast(ui2, *(const us4*)&lds[r][o + 4]);
        ui4 v = { lo.x, lo.y, hi.x, hi.y };
        *(ui4*)(dst + (size_t)id * 8) = v;
    }
}

// ---------------- Pass 2: gather from NHWC bf16 (row-split waves) -----------
__global__ __launch_bounds__(448) void roi_gather_nhwc(
    const u16* __restrict__ ft,      // [N][H][W][CH] bf16
    const float* __restrict__ rois,  // [K][5]
    const int* __restrict__ perm,    // [K] spatial order
    float* __restrict__ out,         // [K][CH][7][7]
    int H, int W, int K, int chunk, int do_swz)
{
    int bid  = blockIdx.x;
    int slot = do_swz ? (bid & 7) * chunk + (bid >> 3) : bid;
    int k    = perm[slot / 7];
    int q    = slot % 7;             // pooled row ph == q
    int bin0 = q * 7;

    __shared__ float lds[7][CH];     // 7 KB

    int lane = threadIdx.x & 63;
    int w    = threadIdx.x >> 6;     // wave = pw (bin col), 0..6
    int half = lane >> 5;            // 0: y0 row, 1: y1 row
    int lc   = lane & 31;            // channel group: ch 8*lc .. 8*lc+7

    const float* rp = rois + (size_t)k * 5;
    int   b   = (int)rp[0];
    float rx1 = rp[1] * SCALE - 0.5f;
    float ry1 = rp[2] * SCALE - 0.5f;
    float rx2 = rp[3] * SCALE - 0.5f;
    float ry2 = rp[4] * SCALE - 0.5f;
    float bin_h = (ry2 - ry1) * (1.0f / POOL_H);
    float bin_w = (rx2 - rx1) * (1.0f / POOL_W);

    const u16* fbase = ft + (size_t)b * H * W * CH + lc * 8;

    int ph = q;
    int pw = w;

    float acc[8];
    #pragma unroll
    for (int j = 0; j < 8; ++j) acc[j] = 0.0f;

    #pragma unroll
    for (int iy = 0; iy < SR; ++iy) {
        float y = ry1 + ((float)ph + ((float)iy + 0.5f) * (1.0f / SR)) * bin_h;
        bool vy = (y > -1.0f) && (y < (float)H);
        float yc = fminf(fmaxf(y, 0.0f), (float)(H - 1));
        int   y0 = (int)yc;
        int   y1 = min(y0 + 1, H - 1);
        float ly = yc - (float)y0;
        float hy = 1.0f - ly;
        int   ysel = half ? y1 : y0;       // per-lane row select
        float wrow = half ? ly : hy;       // per-lane row weight
        #pragma unroll
        for (int ix = 0; ix < SR; ++ix) {
            float x = rx1 + ((float)pw + ((float)ix + 0.5f) * (1.0f / SR)) * bin_w;
            bool vx = (x > -1.0f) && (x < (float)W);
            if (!(vy && vx)) continue;     // wave-uniform branch
            float xc = fminf(fmaxf(x, 0.0f), (float)(W - 1));
            int   x0 = (int)xc;
            int   x1 = min(x0 + 1, W - 1);
            float lx = xc - (float)x0;

            const u16* p0 = fbase + (size_t)(ysel * W + x0) * CH;
            ui4 A = *(const ui4*)p0;                               // (row, x0) 8ch
            ui4 B = *(const ui4*)(p0 + (size_t)(x1 - x0) * CH);    // (row, x1) 8ch

            #pragma unroll
            for (int j = 0; j < 4; ++j) {
                float a0 = bf16lo(A[j]), a1 = bf16hi(A[j]);
                float b0 = bf16lo(B[j]), b1 = bf16hi(B[j]);
                float r0 = a0 + lx * (b0 - a0);
                float r1 = a1 + lx * (b1 - a1);
                acc[2 * j]     += wrow * r0;
                acc[2 * j + 1] += wrow * r1;
            }
        }
    }

    #pragma unroll
    for (int j = 0; j < 8; ++j)
        acc[j] = (acc[j] + __shfl_xor(acc[j], 32, 64)) * 0.25f;

    if (half == 0) {
        f4 lo = { acc[0], acc[1], acc[2], acc[3] };
        f4 hi = { acc[4], acc[5], acc[6], acc[7] };
        *(f4*)&lds[w][lc * 8]     = lo;
        *(f4*)&lds[w][lc * 8 + 4] = hi;
    }
    __syncthreads();

    float* ob = out + (size_t)k * CH * BINS + bin0;
    for (int id = (int)threadIdx.x; id < 7 * CH; id += 448) {
        int c  = id / 7;
        int lb = id % 7;
        ob[(size_t)c * BINS + lb] = lds[lb][c];
    }
}

// ---------------- Fallback (round-3 kernel) if ws too small -----------------
#define NC 2
#define NXCD 8
__global__ __launch_bounds__(256) void roi_align_fallback(
    const float* __restrict__ feat, const float* __restrict__ rois,
    float* __restrict__ out, int C, int H, int W, int K,
    int blocks_per_slice, int slices_per_xcd)
{
    int wgid  = blockIdx.x;
    int g     = wgid % NXCD;
    int r     = wgid / NXCD;
    int slice = g * slices_per_xcd + r / blocks_per_slice;
    int j     = r % blocks_per_slice;
    int tid = j * (int)blockDim.x + (int)threadIdx.x;
    int k   = tid / BINS;
    int bin = tid % BINS;
    if (k >= K) return;
    int pw = bin % POOL_W, ph = bin / POOL_W, c2 = slice;

    const float* rp = rois + (size_t)k * 5;
    int b = (int)rp[0];
    float rx1 = rp[1]*SCALE-0.5f, ry1 = rp[2]*SCALE-0.5f;
    float rx2 = rp[3]*SCALE-0.5f, ry2 = rp[4]*SCALE-0.5f;
    float bin_h = (ry2-ry1)*(1.0f/POOL_H), bin_w = (rx2-rx1)*(1.0f/POOL_W);

    int yr0[SR], yr1[SR]; float ly[SR], hy[SR]; bool vy[SR];
    #pragma unroll
    for (int iy = 0; iy < SR; ++iy) {
        float y = ry1 + ((float)ph + ((float)iy+0.5f)*(1.0f/SR))*bin_h;
        vy[iy] = (y > -1.0f) && (y < (float)H);
        float yc = fminf(fmaxf(y, 0.0f), (float)(H-1));
        int y0 = (int)yc; yr0[iy]=y0; yr1[iy]=min(y0+1,H-1);
        ly[iy]=yc-(float)y0; hy[iy]=1.0f-ly[iy];
    }
    int xl[SR]; float lx[SR]; bool vx[SR], xhi[SR];
    #pragma unroll
    for (int ix = 0; ix < SR; ++ix) {
        float x = rx1 + ((float)pw + ((float)ix+0.5f)*(1.0f/SR))*bin_w;
        vx[ix] = (x > -1.0f) && (x < (float)W);
        float xc = fminf(fmaxf(x, 0.0f), (float)(W-1));
        int x0 = (int)xc; int xload = min(x0, W-2);
        xl[ix]=xload; xhi[ix]=(x0>xload); lx[ix]=xc-(float)x0;
    }
    const size_t HW = (size_t)H*W;
    const float* fmap = feat + ((size_t)b*C + (size_t)c2*NC)*HW;
    float acc[NC];
    #pragma unroll
    for (int cc=0; cc<NC; ++cc) acc[cc]=0.0f;
    #pragma unroll
    for (int iy=0; iy<SR; ++iy)
      #pragma unroll
      for (int ix=0; ix<SR; ++ix)
        if (vy[iy] && vx[ix]) {
            int off0 = yr0[iy]*W + xl[ix], off1 = yr1[iy]*W + xl[ix];
            #pragma unroll
            for (int cc=0; cc<NC; ++cc) {
                const float* base = fmap + (size_t)cc*HW;
                f2v d0 = *(const uf2*)(base + off0);
                f2v d1 = *(const uf2*)(base + off1);
                float v00 = xhi[ix] ? d0.y : d0.x;
                float v10 = xhi[ix] ? d1.y : d1.x;
                float r0 = v00 + lx[ix]*(d0.y - v00);
                float r1 = v10 + lx[ix]*(d1.y - v10);
                acc[cc] += hy[iy]*r0 + ly[iy]*r1;
            }
        }
    size_t obase = ((size_t)k*C + (size_t)c2*NC)*BINS + bin;
    #pragma unroll
    for (int cc=0; cc<NC; ++cc)
        out[obase + (size_t)cc*BINS] = acc[cc]*(1.0f/(SR*SR));
}

extern "C" void kernel_launch(void* const* d_in, const int* in_sizes, int n_in,
                              void* d_out, int out_size, void* d_ws, size_t ws_size,
                              hipStream_t stream) {
    const float* feat = (const float*)d_in[0];
    const float* rois = (const float*)d_in[1];
    float* out = (float*)d_out;

    const int C = 256, H = 200, W = 200;
    const int HW = H * W;
    const int K = in_sizes[1] / 5;
    const int N = in_sizes[0] / (C * HW);

    size_t nhwc_bytes = (size_t)N * HW * CH * sizeof(u16);   // 82 MB for N=4
    size_t need = nhwc_bytes + (size_t)K * sizeof(int);
    if (ws_size >= need && (HW % 64) == 0 && K <= 1024) {
        u16* ft   = (u16*)d_ws;
        int* perm = (int*)((char*)d_ws + nhwc_bytes);
        const int tiles = HW / 64;                           // 625
        nchw_to_nhwc_bf16<<<N * tiles + 1, 512, 0, stream>>>(
            feat, ft, rois, perm, HW, tiles, K, H, W);
        int grid  = K * 7;                                   // 7168 for K=1024
        int swz   = (grid % 8) == 0;
        int chunk = grid / 8;
        roi_gather_nhwc<<<grid, 448, 0, stream>>>(
            (const u16*)ft, rois, perm, out, H, W, K, chunk, swz);
    } else {
        const int threads_per_slice = K * BINS;
        const int block = 256;
        const int blocks_per_slice = (threads_per_slice + block - 1) / block;
        const int slices = C / NC;
        const int slices_per_xcd = slices / NXCD;
        const int grid = slices * blocks_per_slice;
        roi_align_fallback<<<grid, block, 0, stream>>>(feat, rois, out, C, H, W, K,
                                                       blocks_per_slice, slices_per_xcd);
    }
}

// Round 9
// 91.856 us; speedup vs baseline: 2.8435x; 1.0103x over previous
//
#include <hip/hip_runtime.h>

#define POOL_H 7
#define POOL_W 7
#define BINS   49
#define SR 2
#define SCALE 0.25f
#define CH 256          // channels (fixed by problem)

typedef unsigned int   u32;
typedef unsigned short u16;
typedef unsigned long long u64;
typedef float f2v __attribute__((ext_vector_type(2)));
typedef f2v uf2 __attribute__((aligned(4)));
typedef float f4  __attribute__((ext_vector_type(4)));
typedef u32  ui4 __attribute__((ext_vector_type(4)));

__device__ __forceinline__ u16 f32_to_bf16_rne(float f) {
    u32 u = __builtin_bit_cast(u32, f);
    u32 r = (u + 0x7FFFu + ((u >> 16) & 1u)) >> 16;
    return (u16)r;
}
__device__ __forceinline__ float bf16lo(u32 u) { return __builtin_bit_cast(float, u << 16); }
__device__ __forceinline__ float bf16hi(u32 u) { return __builtin_bit_cast(float, u & 0xFFFF0000u); }

// ---------------- Pass 1: NCHW f32 -> NHWC bf16 transpose + ROI spatial sort
// Tile = 128 hw x 256 c. Reads are dwordx2/lane = 512B contiguous per wave
// (vs 256B before — targets DRAM page efficiency at the 160KB channel stride).
// LDS: u32 lds32[c][m] with rotation swizzle word = c*64 + ((m + (c>>3)) & 63)
//  - write phase (lanes span m, c uniform): banks (l + g) & 63 -> conflict-free
//  - chunk phase (lanes span cg):           banks (cg + q) mod 32 -> conflict-free
// Stores: 1KB contiguous per wave (dwordx4/lane).
__global__ __launch_bounds__(512) void nchw_to_nhwc_bf16(
    const float* __restrict__ feat, u16* __restrict__ ft,
    const float* __restrict__ rois, int* __restrict__ perm,
    int HW, int tiles, int K, int H, int W)
{
    extern __shared__ __align__(16) unsigned char smem[];   // 64 KB dynamic

    int t = threadIdx.x;

    if ((int)blockIdx.x == gridDim.x - 1) {
        // ---- ROI spatial sort (K <= 1024), 8KB of smem ----
        u64* keys = (u64*)smem;
        int bd = (int)blockDim.x;
        for (int v = t; v < 1024; v += bd) {
            u64 kv = ~0ull;
            if (v < K) {
                const float* rp = rois + (size_t)v * 5;
                int b = (int)rp[0];
                float cx = 0.5f * (rp[1] + rp[3]) * SCALE;
                float cy = 0.5f * (rp[2] + rp[4]) * SCALE;
                int qx = min(15, max(0, (int)(cx * (16.0f / (float)W))));
                int qy = min(15, max(0, (int)(cy * (16.0f / (float)H))));
                u32 m = 0;
                #pragma unroll
                for (int i = 0; i < 4; ++i)
                    m |= (((qy >> i) & 1u) << (2 * i + 1)) | (((qx >> i) & 1u) << (2 * i));
                u32 key = ((u32)b << 8) | m;
                kv = ((u64)key << 32) | (u32)v;
            }
            keys[v] = kv;
        }
        __syncthreads();
        for (int size = 2; size <= 1024; size <<= 1) {
            for (int stride = size >> 1; stride > 0; stride >>= 1) {
                for (int v = t; v < 1024; v += bd) {
                    int j = v ^ stride;
                    if (j > v) {
                        bool up = ((v & size) == 0);
                        u64 a = keys[v], bb = keys[j];
                        if ((a > bb) == up) { keys[v] = bb; keys[j] = a; }
                    }
                }
                __syncthreads();
            }
        }
        for (int v = t; v < K; v += bd)
            perm[v] = (int)(keys[v] & 0xffffffffu);
        return;
    }

    u32* lds32 = (u32*)smem;            // logical [256][64] u32, swizzled
    int b    = blockIdx.x / tiles;
    int tile = blockIdx.x % tiles;
    int hw0  = tile * 128;
    int nhw  = min(128, HW - hw0);      // 128 or 64 (40000 = 312*128 + 64)

    int lane = t & 63;
    int w    = t >> 6;                  // 0..7

    const float* src = feat + (size_t)b * CH * HW + hw0;
    if (nhw == 128) {
        #pragma unroll 8
        for (int ci = 0; ci < 32; ++ci) {
            int c = w * 32 + ci;
            f2v v = *(const f2v*)(src + (size_t)c * HW + 2 * lane);
            u32 p = ((u32)f32_to_bf16_rne(v.y) << 16) | (u32)f32_to_bf16_rne(v.x);
            lds32[c * 64 + ((lane + (c >> 3)) & 63)] = p;
        }
    } else {
        #pragma unroll 8
        for (int ci = 0; ci < 32; ++ci) {
            int c = w * 32 + ci;
            float v = src[(size_t)c * HW + lane];
            u16 h = f32_to_bf16_rne(v);
            u16* ph = (u16*)&lds32[c * 64 + (((lane >> 1) + (c >> 3)) & 63)];
            ph[lane & 1] = h;
        }
    }
    __syncthreads();

    // Store: 16B NHWC chunk per thread-iter; wave writes 1KB contiguous.
    u16* dst = ft + ((size_t)b * HW + hw0) * CH;
    int cg     = t & 31;                // channel group: c = 8*cg .. 8*cg+7
    int hw_off = t >> 5;                // [0,16)
    int iters  = nhw >> 4;              // 8 or 4
    for (int i = 0; i < iters; ++i) {
        int hw  = i * 16 + hw_off;
        int m   = hw >> 1;
        int sel = hw & 1;
        u32 vals[8];
        #pragma unroll
        for (int j = 0; j < 8; ++j) {
            int c = 8 * cg + j;
            vals[j] = lds32[c * 64 + ((m + cg) & 63)];
        }
        ui4 o;
        #pragma unroll
        for (int d = 0; d < 4; ++d) {
            u32 lo16 = sel ? (vals[2 * d]     >> 16) : (vals[2 * d]     & 0xFFFFu);
            u32 hi16 = sel ? (vals[2 * d + 1] >> 16) : (vals[2 * d + 1] & 0xFFFFu);
            o[d] = (hi16 << 16) | lo16;
        }
        *(ui4*)(dst + (size_t)hw * CH + cg * 8) = o;
    }
}

// ---------------- Pass 2: gather from NHWC bf16 (row-split waves) -----------
__global__ __launch_bounds__(448) void roi_gather_nhwc(
    const u16* __restrict__ ft,      // [N][H][W][CH] bf16
    const float* __restrict__ rois,  // [K][5]
    const int* __restrict__ perm,    // [K] spatial order
    float* __restrict__ out,         // [K][CH][7][7]
    int H, int W, int K, int chunk, int do_swz)
{
    int bid  = blockIdx.x;
    int slot = do_swz ? (bid & 7) * chunk + (bid >> 3) : bid;
    int k    = perm[slot / 7];
    int q    = slot % 7;             // pooled row ph == q
    int bin0 = q * 7;

    __shared__ float lds[7][CH];     // 7 KB

    int lane = threadIdx.x & 63;
    int w    = threadIdx.x >> 6;     // wave = pw (bin col), 0..6
    int half = lane >> 5;            // 0: y0 row, 1: y1 row
    int lc   = lane & 31;            // channel group: ch 8*lc .. 8*lc+7

    const float* rp = rois + (size_t)k * 5;
    int   b   = (int)rp[0];
    float rx1 = rp[1] * SCALE - 0.5f;
    float ry1 = rp[2] * SCALE - 0.5f;
    float rx2 = rp[3] * SCALE - 0.5f;
    float ry2 = rp[4] * SCALE - 0.5f;
    float bin_h = (ry2 - ry1) * (1.0f / POOL_H);
    float bin_w = (rx2 - rx1) * (1.0f / POOL_W);

    const u16* fbase = ft + (size_t)b * H * W * CH + lc * 8;

    int ph = q;
    int pw = w;

    float acc[8];
    #pragma unroll
    for (int j = 0; j < 8; ++j) acc[j] = 0.0f;

    #pragma unroll
    for (int iy = 0; iy < SR; ++iy) {
        float y = ry1 + ((float)ph + ((float)iy + 0.5f) * (1.0f / SR)) * bin_h;
        bool vy = (y > -1.0f) && (y < (float)H);
        float yc = fminf(fmaxf(y, 0.0f), (float)(H - 1));
        int   y0 = (int)yc;
        int   y1 = min(y0 + 1, H - 1);
        float ly = yc - (float)y0;
        float hy = 1.0f - ly;
        int   ysel = half ? y1 : y0;       // per-lane row select
        float wrow = half ? ly : hy;       // per-lane row weight
        #pragma unroll
        for (int ix = 0; ix < SR; ++ix) {
            float x = rx1 + ((float)pw + ((float)ix + 0.5f) * (1.0f / SR)) * bin_w;
            bool vx = (x > -1.0f) && (x < (float)W);
            if (!(vy && vx)) continue;     // wave-uniform branch
            float xc = fminf(fmaxf(x, 0.0f), (float)(W - 1));
            int   x0 = (int)xc;
            int   x1 = min(x0 + 1, W - 1);
            float lx = xc - (float)x0;

            const u16* p0 = fbase + (size_t)(ysel * W + x0) * CH;
            ui4 A = *(const ui4*)p0;                               // (row, x0) 8ch
            ui4 B = *(const ui4*)(p0 + (size_t)(x1 - x0) * CH);    // (row, x1) 8ch

            #pragma unroll
            for (int j = 0; j < 4; ++j) {
                float a0 = bf16lo(A[j]), a1 = bf16hi(A[j]);
                float b0 = bf16lo(B[j]), b1 = bf16hi(B[j]);
                float r0 = a0 + lx * (b0 - a0);
                float r1 = a1 + lx * (b1 - a1);
                acc[2 * j]     += wrow * r0;
                acc[2 * j + 1] += wrow * r1;
            }
        }
    }

    #pragma unroll
    for (int j = 0; j < 8; ++j)
        acc[j] = (acc[j] + __shfl_xor(acc[j], 32, 64)) * 0.25f;

    if (half == 0) {
        f4 lo = { acc[0], acc[1], acc[2], acc[3] };
        f4 hi = { acc[4], acc[5], acc[6], acc[7] };
        *(f4*)&lds[w][lc * 8]     = lo;
        *(f4*)&lds[w][lc * 8 + 4] = hi;
    }
    __syncthreads();

    float* ob = out + (size_t)k * CH * BINS + bin0;
    for (int id = (int)threadIdx.x; id < 7 * CH; id += 448) {
        int c  = id / 7;
        int lb = id % 7;
        ob[(size_t)c * BINS + lb] = lds[lb][c];
    }
}

// ---------------- Fallback (round-3 kernel) if ws too small -----------------
#define NC 2
#define NXCD 8
__global__ __launch_bounds__(256) void roi_align_fallback(
    const float* __restrict__ feat, const float* __restrict__ rois,
    float* __restrict__ out, int C, int H, int W, int K,
    int blocks_per_slice, int slices_per_xcd)
{
    int wgid  = blockIdx.x;
    int g     = wgid % NXCD;
    int r     = wgid / NXCD;
    int slice = g * slices_per_xcd + r / blocks_per_slice;
    int j     = r % blocks_per_slice;
    int tid = j * (int)blockDim.x + (int)threadIdx.x;
    int k   = tid / BINS;
    int bin = tid % BINS;
    if (k >= K) return;
    int pw = bin % POOL_W, ph = bin / POOL_W, c2 = slice;

    const float* rp = rois + (size_t)k * 5;
    int b = (int)rp[0];
    float rx1 = rp[1]*SCALE-0.5f, ry1 = rp[2]*SCALE-0.5f;
    float rx2 = rp[3]*SCALE-0.5f, ry2 = rp[4]*SCALE-0.5f;
    float bin_h = (ry2-ry1)*(1.0f/POOL_H), bin_w = (rx2-rx1)*(1.0f/POOL_W);

    int yr0[SR], yr1[SR]; float ly[SR], hy[SR]; bool vy[SR];
    #pragma unroll
    for (int iy = 0; iy < SR; ++iy) {
        float y = ry1 + ((float)ph + ((float)iy+0.5f)*(1.0f/SR))*bin_h;
        vy[iy] = (y > -1.0f) && (y < (float)H);
        float yc = fminf(fmaxf(y, 0.0f), (float)(H-1));
        int y0 = (int)yc; yr0[iy]=y0; yr1[iy]=min(y0+1,H-1);
        ly[iy]=yc-(float)y0; hy[iy]=1.0f-ly[iy];
    }
    int xl[SR]; float lx[SR]; bool vx[SR], xhi[SR];
    #pragma unroll
    for (int ix = 0; ix < SR; ++ix) {
        float x = rx1 + ((float)pw + ((float)ix+0.5f)*(1.0f/SR))*bin_w;
        vx[ix] = (x > -1.0f) && (x < (float)W);
        float xc = fminf(fmaxf(x, 0.0f), (float)(W-1));
        int x0 = (int)xc; int xload = min(x0, W-2);
        xl[ix]=xload; xhi[ix]=(x0>xload); lx[ix]=xc-(float)x0;
    }
    const size_t HW = (size_t)H*W;
    const float* fmap = feat + ((size_t)b*C + (size_t)c2*NC)*HW;
    float acc[NC];
    #pragma unroll
    for (int cc=0; cc<NC; ++cc) acc[cc]=0.0f;
    #pragma unroll
    for (int iy=0; iy<SR; ++iy)
      #pragma unroll
      for (int ix=0; ix<SR; ++ix)
        if (vy[iy] && vx[ix]) {
            int off0 = yr0[iy]*W + xl[ix], off1 = yr1[iy]*W + xl[ix];
            #pragma unroll
            for (int cc=0; cc<NC; ++cc) {
                const float* base = fmap + (size_t)cc*HW;
                f2v d0 = *(const uf2*)(base + off0);
                f2v d1 = *(const uf2*)(base + off1);
                float v00 = xhi[ix] ? d0.y : d0.x;
                float v10 = xhi[ix] ? d1.y : d1.x;
                float r0 = v00 + lx[ix]*(d0.y - v00);
                float r1 = v10 + lx[ix]*(d1.y - v10);
                acc[cc] += hy[iy]*r0 + ly[iy]*r1;
            }
        }
    size_t obase = ((size_t)k*C + (size_t)c2*NC)*BINS + bin;
    #pragma unroll
    for (int cc=0; cc<NC; ++cc)
        out[obase + (size_t)cc*BINS] = acc[cc]*(1.0f/(SR*SR));
}

extern "C" void kernel_launch(void* const* d_in, const int* in_sizes, int n_in,
                              void* d_out, int out_size, void* d_ws, size_t ws_size,
                              hipStream_t stream) {
    const float* feat = (const float*)d_in[0];
    const float* rois = (const float*)d_in[1];
    float* out = (float*)d_out;

    const int C = 256, H = 200, W = 200;
    const int HW = H * W;
    const int K = in_sizes[1] / 5;
    const int N = in_sizes[0] / (C * HW);

    size_t nhwc_bytes = (size_t)N * HW * CH * sizeof(u16);   // 82 MB for N=4
    size_t need = nhwc_bytes + (size_t)K * sizeof(int);
    if (ws_size >= need && (HW % 64) == 0 && K <= 1024) {
        u16* ft   = (u16*)d_ws;
        int* perm = (int*)((char*)d_ws + nhwc_bytes);
        const int tiles = (HW + 127) / 128;                  // 313
        nchw_to_nhwc_bf16<<<N * tiles + 1, 512, 65536, stream>>>(
            feat, ft, rois, perm, HW, tiles, K, H, W);
        int grid  = K * 7;                                   // 7168 for K=1024
        int swz   = (grid % 8) == 0;
        int chunk = grid / 8;
        roi_gather_nhwc<<<grid, 448, 0, stream>>>(
            (const u16*)ft, rois, perm, out, H, W, K, chunk, swz);
    } else {
        const int threads_per_slice = K * BINS;
        const int block = 256;
        const int blocks_per_slice = (threads_per_slice + block - 1) / block;
        const int slices = C / NC;
        const int slices_per_xcd = slices / NXCD;
        const int grid = slices * blocks_per_slice;
        roi_align_fallback<<<grid, block, 0, stream>>>(feat, rois, out, C, H, W, K,
                                                       blocks_per_slice, slices_per_xcd);
    }
}